// Round 1
// baseline (6219.632 us; speedup 1.0000x reference)
//
#include <hip/hip_runtime.h>

#define NPADC 40
#define NZ 26
#define NX 120
#define NZP 106   // NZ + 2*NPADC
#define NXP 200   // NX + 2*NPADC
#define NCELL (NZP * NXP)

// ---- damp profile, matching _damp_profile in fp32 ----
__device__ __forceinline__ float dprof(int idx, int n) {
#pragma clang fp contract(off)
    float fi = (float)idx;
    float left = 1.0f, right = 1.0f;
    if (idx < NPADC) {
        float a = 0.015f * ((float)NPADC - fi);
        left = expf(-(a * a));
    }
    if (idx >= n - NPADC) {
        float a = 0.015f * (fi - (float)(n - NPADC - 1));
        right = expf(-(a * a));
    }
    return left * right;
}

// ---- one-time setup: coefficients + damp + field init + illum zero ----
__global__ void setup_kernel(const float* __restrict__ vp,
                             const float* __restrict__ vs,
                             const float* __restrict__ den,
                             const float* __restrict__ ivec,
                             const float* __restrict__ temp,
                             float* __restrict__ fields,   // 5*NCELL (d_out uu1 region)
                             float* __restrict__ illum,    // NCELL
                             float* __restrict__ ca,
                             float* __restrict__ cl,
                             float* __restrict__ dtcm,
                             float* __restrict__ b,
                             float* __restrict__ damp) {
#pragma clang fp contract(off)
    int i = blockIdx.x * blockDim.x + threadIdx.x;
    if (i >= NCELL) return;
    int z = i / NXP;
    int x = i - z * NXP;

    float dtx = ivec[3];

    // edge-padded vp/vs via clamped indices (jnp.pad mode='edge')
    int zi = z - NPADC; zi = zi < 0 ? 0 : (zi > NZ - 1 ? NZ - 1 : zi);
    int xi = x - NPADC; xi = xi < 0 ? 0 : (xi > NX - 1 ? NX - 1 : xi);
    float vpv = vp[zi * NX + xi];
    float vsv = vs[zi * NX + xi];
    float d = den[i];

    float cav = (vpv * vpv) * d;   // ca = vp1**2 * den
    float cmv = (vsv * vsv) * d;   // cm = vs1**2 * den
    ca[i] = cav;
    cl[i] = cav - 2.0f * cmv;      // cl = ca - 2*cm
    dtcm[i] = dtx * cmv;           // (dtx * cm) as evaluated left-assoc in ref
    b[i] = dtx / d;                // b = dtx / den
    damp[i] = dprof(z, NZP) * dprof(x, NXP);

    // initial carry from temp; illum zeroed
    for (int f = 0; f < 5; ++f)
        fields[f * NCELL + i] = temp[f * NCELL + i];
    illum[i] = 0.0f;
}

// ---- phase A: velocity update + seismogram record ----
__global__ void vel_kernel(float* __restrict__ vx, float* __restrict__ vz,
                           const float* __restrict__ txx,
                           const float* __restrict__ tzz,
                           const float* __restrict__ txz,
                           const float* __restrict__ b,
                           const float* __restrict__ damp,
                           float* __restrict__ seismo, int t) {
#pragma clang fp contract(off)
    int i = blockIdx.x * blockDim.x + threadIdx.x;
    if (i >= NCELL) return;
    int z = i / NXP;
    int x = i - z * NXP;
    // jnp.roll wraparound neighbors
    int xp = (x == NXP - 1) ? i - (NXP - 1) : i + 1;
    int xm = (x == 0) ? i + (NXP - 1) : i - 1;
    int zp = (z == NZP - 1) ? i - (NZP - 1) * NXP : i + NXP;
    int zm = (z == 0) ? i + (NZP - 1) * NXP : i - NXP;

    float bv = b[i];
    float dv = damp[i];

    // vx = (vx + b*(dxp(txx) + dzm(txz))) * damp
    float t1 = txx[xp] - txx[i];
    float t2 = txz[i] - txz[zm];
    float nvx = (vx[i] + bv * (t1 + t2)) * dv;

    // vz = (vz + b*(dzp(tzz) + dxm(txz))) * damp
    float t3 = tzz[zp] - tzz[i];
    float t4 = txz[i] - txz[xm];
    float nvz = (vz[i] + bv * (t3 + t4)) * dv;

    vx[i] = nvx;
    vz[i] = nvz;

    // rec = vz[NPAD+1, NPAD:NPAD+NX] recorded after the velocity update
    if (z == NPADC + 1 && x >= NPADC && x < NPADC + NX)
        seismo[t * NX + (x - NPADC)] = nvz;
}

// ---- phase B: stress update + source + illum ----
__global__ void stress_kernel(const float* __restrict__ vx,
                              const float* __restrict__ vz,
                              float* __restrict__ txx, float* __restrict__ tzz,
                              float* __restrict__ txz,
                              const float* __restrict__ ca,
                              const float* __restrict__ cl,
                              const float* __restrict__ dtcm,
                              const float* __restrict__ damp,
                              const float* __restrict__ ivec,
                              const float* __restrict__ s,
                              const int* __restrict__ isz_p,
                              const int* __restrict__ isx_p,
                              float* __restrict__ illum, int t) {
#pragma clang fp contract(off)
    int i = blockIdx.x * blockDim.x + threadIdx.x;
    if (i >= NCELL) return;
    int z = i / NXP;
    int x = i - z * NXP;
    int xp = (x == NXP - 1) ? i - (NXP - 1) : i + 1;
    int xm = (x == 0) ? i + (NXP - 1) : i - 1;
    int zp = (z == NZP - 1) ? i - (NZP - 1) * NXP : i + NXP;
    int zm = (z == 0) ? i + (NZP - 1) * NXP : i - NXP;

    float dtx = ivec[3];
    float dt = ivec[2];
    float dv = damp[i];

    float exx = vx[i] - vx[xm];   // dxm(vx)
    float ezz = vz[i] - vz[zm];   // dzm(vz)

    // txx = (txx + dtx*(ca*exx + cl*ezz)) * damp
    float e1 = ca[i] * exx;
    float e2 = cl[i] * ezz;
    float ntxx = (txx[i] + dtx * (e1 + e2)) * dv;

    // tzz = (tzz + dtx*(cl*exx + ca*ezz)) * damp
    float e3 = cl[i] * exx;
    float e4 = ca[i] * ezz;
    float ntzz = (tzz[i] + dtx * (e3 + e4)) * dv;

    // txz = (txz + (dtx*cm)*(dzp(vx) + dxp(vz))) * damp
    float p1 = vx[zp] - vx[i];
    float p2 = vz[xp] - vz[i];
    float ntxz = (txz[i] + dtcm[i] * (p1 + p2)) * dv;

    // source injection AFTER damping (txx.at[isz,isx].add(src*dt))
    if (z == *isz_p && x == *isx_p) {
        float sv = s[t] * dt;
        ntxx += sv;
        ntzz += sv;
    }

    txx[i] = ntxx;
    tzz[i] = ntzz;
    txz[i] = ntxz;

    float divv = exx + ezz;
    illum[i] = illum[i] + divv * divv;
}

extern "C" void kernel_launch(void* const* d_in, const int* in_sizes, int n_in,
                              void* d_out, int out_size, void* d_ws, size_t ws_size,
                              hipStream_t stream) {
    const float* vp   = (const float*)d_in[0];
    const float* vs   = (const float*)d_in[1];
    const float* den  = (const float*)d_in[2];
    const float* ivec = (const float*)d_in[3];
    const float* temp = (const float*)d_in[4];
    const float* s    = (const float*)d_in[5];
    const int*   isz  = (const int*)d_in[7];
    const int*   isx  = (const int*)d_in[8];
    int nt = in_sizes[5];   // length of source wavelet == nt

    float* out    = (float*)d_out;
    float* fields = out;                    // uu1: 5*NCELL — used as live state
    float* seismo = out + 5 * NCELL;        // nt*NX
    float* illum  = seismo + (size_t)nt * NX; // NCELL

    float* ws   = (float*)d_ws;
    float* ca   = ws;
    float* cl   = ws + NCELL;
    float* dtcm = ws + 2 * NCELL;
    float* b    = ws + 3 * NCELL;
    float* damp = ws + 4 * NCELL;

    dim3 blk(256);
    dim3 grd((NCELL + 255) / 256);

    setup_kernel<<<grd, blk, 0, stream>>>(vp, vs, den, ivec, temp,
                                          fields, illum, ca, cl, dtcm, b, damp);

    float* vx  = fields;
    float* vz  = fields + NCELL;
    float* txx = fields + 2 * NCELL;
    float* tzz = fields + 3 * NCELL;
    float* txz = fields + 4 * NCELL;

    for (int t = 0; t < nt; ++t) {
        vel_kernel<<<grd, blk, 0, stream>>>(vx, vz, txx, tzz, txz, b, damp, seismo, t);
        stress_kernel<<<grd, blk, 0, stream>>>(vx, vz, txx, tzz, txz,
                                               ca, cl, dtcm, damp, ivec, s,
                                               isz, isx, illum, t);
    }
}

// Round 2
// 3826.059 us; speedup vs baseline: 1.6256x; 1.6256x over previous
//
#include <hip/hip_runtime.h>

#define NPADC 40
#define NZ 26
#define NXI 120            // interior nx (seismo width)
#define NZP 106
#define NXP 200
#define NCELL (NZP * NXP)

#define KSTEPS 5
#define HALO (2 * KSTEPS)          // 10
#define TZ 14
#define TX 25
#define ZB 8                       // ceil(106/14): 7*14=98, last tile tz=8
#define XB 8                       // 200/25 exact
#define EXT_X (TX + 2 * HALO)      // 45
#define EZMAX (TZ + 2 * HALO)      // 34
#define LDSN (EZMAX * EXT_X)       // 1530
#define NTHREADS 512

// ---- damp profile, matching _damp_profile in fp32 ----
__device__ __forceinline__ float dprof(int idx, int n) {
#pragma clang fp contract(off)
    float fi = (float)idx;
    float left = 1.0f, right = 1.0f;
    if (idx < NPADC) {
        float a = 0.015f * ((float)NPADC - fi);
        left = expf(-(a * a));
    }
    if (idx >= n - NPADC) {
        float a = 0.015f * (fi - (float)(n - NPADC - 1));
        right = expf(-(a * a));
    }
    return left * right;
}

// ---- one-time setup: coefficients into ws, init state buf0, zero illum ----
// coeff layout in ws: [b, damp, ca, cl, dtcm], each NCELL floats
__global__ void setup_kernel(const float* __restrict__ vp,
                             const float* __restrict__ vs,
                             const float* __restrict__ den,
                             const float* __restrict__ ivec,
                             const float* __restrict__ temp,
                             float* __restrict__ coeff,
                             float* __restrict__ buf0,
                             float* __restrict__ illum) {
#pragma clang fp contract(off)
    int i = blockIdx.x * blockDim.x + threadIdx.x;
    if (i >= NCELL) return;
    int z = i / NXP;
    int x = i - z * NXP;

    float dtx = ivec[3];

    int zi = z - NPADC; zi = zi < 0 ? 0 : (zi > NZ - 1 ? NZ - 1 : zi);
    int xi = x - NPADC; xi = xi < 0 ? 0 : (xi > NXI - 1 ? NXI - 1 : xi);
    float vpv = vp[zi * NXI + xi];
    float vsv = vs[zi * NXI + xi];
    float d = den[i];

    float cav = (vpv * vpv) * d;     // ca = vp1**2 * den
    float cmv = (vsv * vsv) * d;     // cm = vs1**2 * den
    coeff[0 * NCELL + i] = dtx / d;             // b
    coeff[1 * NCELL + i] = dprof(z, NZP) * dprof(x, NXP);  // damp
    coeff[2 * NCELL + i] = cav;                 // ca
    coeff[3 * NCELL + i] = cav - 2.0f * cmv;    // cl
    coeff[4 * NCELL + i] = dtx * cmv;           // dtx*cm

    for (int f = 0; f < 5; ++f)
        buf0[f * NCELL + i] = temp[f * NCELL + i];
    illum[i] = 0.0f;
}

// ---- fused K-step trapezoid kernel ----
// lds field order: 0=vx 1=vz 2=txx 3=tzz 4=txz 5=b 6=damp 7=ca 8=cl 9=dtcm
__global__ __launch_bounds__(NTHREADS)
void fused_kernel(const float* __restrict__ src, float* __restrict__ dst,
                  const float* __restrict__ coeff,
                  const float* __restrict__ ivec,
                  const float* __restrict__ s,
                  const int* __restrict__ iszp, const int* __restrict__ isxp,
                  float* __restrict__ illum, float* __restrict__ seismo,
                  int t0, int ks) {
#pragma clang fp contract(off)
    __shared__ float lds[10][LDSN];
    __shared__ float lill[TZ * TX];

    const int tid = threadIdx.x;
    const int zb = blockIdx.x / XB, xb = blockIdx.x - zb * XB;
    const int z0 = zb * TZ, x0 = xb * TX;
    const int tzb = (NZP - z0 < TZ) ? (NZP - z0) : TZ;   // 14 or 8
    const int ez = tzb + 2 * HALO;                        // 34 or 28
    const int ncells = ez * EXT_X;
    const float dt  = ivec[2];
    const float dtx = ivec[3];
    const int isz = *iszp, isx = *isxp;

    // ---- load ext tile: 5 fields + 5 coeffs (periodic wrap) ----
    for (int rc = tid; rc < ncells; rc += NTHREADS) {
        int iz = rc / EXT_X, ix = rc - iz * EXT_X;
        int gz = z0 - HALO + iz; gz += (gz < 0) ? NZP : 0; gz -= (gz >= NZP) ? NZP : 0;
        int gx = x0 - HALO + ix; gx += (gx < 0) ? NXP : 0; gx -= (gx >= NXP) ? NXP : 0;
        int g = gz * NXP + gx;
        lds[0][rc] = src[0 * NCELL + g];
        lds[1][rc] = src[1 * NCELL + g];
        lds[2][rc] = src[2 * NCELL + g];
        lds[3][rc] = src[3 * NCELL + g];
        lds[4][rc] = src[4 * NCELL + g];
        lds[5][rc] = coeff[0 * NCELL + g];
        lds[6][rc] = coeff[1 * NCELL + g];
        lds[7][rc] = coeff[2 * NCELL + g];
        lds[8][rc] = coeff[3 * NCELL + g];
        lds[9][rc] = coeff[4 * NCELL + g];
    }
    // illum interior accumulator
    for (int rc = tid; rc < tzb * TX; rc += NTHREADS) {
        int liz = rc / TX, lix = rc - liz * TX;
        lill[rc] = illum[(z0 + liz) * NXP + (x0 + lix)];
    }
    __syncthreads();

    // ---- 2*ks phases, computable region shrinks by 1 ring per phase ----
    for (int p = 1; p <= 2 * ks; ++p) {
        const int k = (p + 1) >> 1;       // local step 1..ks
        const int t = t0 + k - 1;         // global step index
        const int lo = p, hiZ = ez - p, hiX = EXT_X - p;

        if (p & 1) {
            // velocity phase
            for (int rc = tid; rc < ncells; rc += NTHREADS) {
                int iz = rc / EXT_X, ix = rc - iz * EXT_X;
                if (iz < lo || iz >= hiZ || ix < lo || ix >= hiX) continue;
                float bv = lds[5][rc], dv = lds[6][rc];
                float t1 = lds[2][rc + 1]     - lds[2][rc];      // dxp(txx)
                float t2 = lds[4][rc]         - lds[4][rc - EXT_X]; // dzm(txz)
                float nvx = (lds[0][rc] + bv * (t1 + t2)) * dv;
                float t3 = lds[3][rc + EXT_X] - lds[3][rc];      // dzp(tzz)
                float t4 = lds[4][rc]         - lds[4][rc - 1];  // dxm(txz)
                float nvz = (lds[1][rc] + bv * (t3 + t4)) * dv;
                lds[0][rc] = nvx;
                lds[1][rc] = nvz;
                // seismogram: owner interior, row NPAD+1
                int liz = iz - HALO, lix = ix - HALO;
                if (liz >= 0 && liz < tzb && lix >= 0 && lix < TX) {
                    int gz = z0 + liz, gx = x0 + lix;
                    if (gz == NPADC + 1 && gx >= NPADC && gx < NPADC + NXI)
                        seismo[t * NXI + (gx - NPADC)] = nvz;
                }
            }
        } else {
            // stress phase
            for (int rc = tid; rc < ncells; rc += NTHREADS) {
                int iz = rc / EXT_X, ix = rc - iz * EXT_X;
                if (iz < lo || iz >= hiZ || ix < lo || ix >= hiX) continue;
                float dv = lds[6][rc];
                float exx = lds[0][rc] - lds[0][rc - 1];         // dxm(vx)
                float ezz = lds[1][rc] - lds[1][rc - EXT_X];     // dzm(vz)
                float e1 = lds[7][rc] * exx;
                float e2 = lds[8][rc] * ezz;
                float ntxx = (lds[2][rc] + dtx * (e1 + e2)) * dv;
                float e3 = lds[8][rc] * exx;
                float e4 = lds[7][rc] * ezz;
                float ntzz = (lds[3][rc] + dtx * (e3 + e4)) * dv;
                float p1 = lds[0][rc + EXT_X] - lds[0][rc];      // dzp(vx)
                float p2 = lds[1][rc + 1]     - lds[1][rc];      // dxp(vz)
                float ntxz = (lds[4][rc] + lds[9][rc] * (p1 + p2)) * dv;
                // source injection after damping
                int gz = z0 - HALO + iz; gz += (gz < 0) ? NZP : 0; gz -= (gz >= NZP) ? NZP : 0;
                int gx = x0 - HALO + ix; gx += (gx < 0) ? NXP : 0; gx -= (gx >= NXP) ? NXP : 0;
                if (gz == isz && gx == isx) {
                    float sv = s[t] * dt;
                    ntxx += sv;
                    ntzz += sv;
                }
                lds[2][rc] = ntxx;
                lds[3][rc] = ntzz;
                lds[4][rc] = ntxz;
                // illum accumulation (owner interior)
                int liz = iz - HALO, lix = ix - HALO;
                if (liz >= 0 && liz < tzb && lix >= 0 && lix < TX) {
                    float divv = exx + ezz;
                    lill[liz * TX + lix] += divv * divv;
                }
            }
        }
        __syncthreads();
    }

    // ---- store interior back ----
    for (int rc = tid; rc < tzb * TX; rc += NTHREADS) {
        int liz = rc / TX, lix = rc - liz * TX;
        int g = (z0 + liz) * NXP + (x0 + lix);
        int e = (liz + HALO) * EXT_X + (lix + HALO);
        dst[0 * NCELL + g] = lds[0][e];
        dst[1 * NCELL + g] = lds[1][e];
        dst[2 * NCELL + g] = lds[2][e];
        dst[3 * NCELL + g] = lds[3][e];
        dst[4 * NCELL + g] = lds[4][e];
        illum[g] = lill[rc];
    }
}

// ---- final copy of state into d_out ----
__global__ void copy_kernel(const float* __restrict__ src, float* __restrict__ dst, int n) {
    int i = blockIdx.x * blockDim.x + threadIdx.x;
    if (i < n) dst[i] = src[i];
}

extern "C" void kernel_launch(void* const* d_in, const int* in_sizes, int n_in,
                              void* d_out, int out_size, void* d_ws, size_t ws_size,
                              hipStream_t stream) {
    const float* vp   = (const float*)d_in[0];
    const float* vs   = (const float*)d_in[1];
    const float* den  = (const float*)d_in[2];
    const float* ivec = (const float*)d_in[3];
    const float* temp = (const float*)d_in[4];
    const float* s    = (const float*)d_in[5];
    const int*   isz  = (const int*)d_in[7];
    const int*   isx  = (const int*)d_in[8];
    int nt = in_sizes[5];

    float* out    = (float*)d_out;
    float* fields = out;                        // uu1: 5*NCELL
    float* seismo = out + 5 * NCELL;            // nt*NXI
    float* illum  = seismo + (size_t)nt * NXI;  // NCELL

    float* ws    = (float*)d_ws;
    float* coeff = ws;                 // 5*NCELL
    float* buf0  = ws + 5 * NCELL;     // 5*NCELL
    float* buf1  = ws + 10 * NCELL;    // 5*NCELL

    setup_kernel<<<(NCELL + 255) / 256, 256, 0, stream>>>(
        vp, vs, den, ivec, temp, coeff, buf0, illum);

    int t0 = 0;
    int i = 0;
    while (t0 < nt) {
        int ks = (nt - t0 >= KSTEPS) ? KSTEPS : (nt - t0);
        const float* sb = (i & 1) ? buf1 : buf0;
        float*       db = (i & 1) ? buf0 : buf1;
        fused_kernel<<<ZB * XB, NTHREADS, 0, stream>>>(
            sb, db, coeff, ivec, s, isz, isx, illum, seismo, t0, ks);
        t0 += ks;
        ++i;
    }
    const float* finalbuf = (i & 1) ? buf1 : buf0;
    copy_kernel<<<(5 * NCELL + 255) / 256, 256, 0, stream>>>(finalbuf, fields, 5 * NCELL);
}

// Round 3
// 3532.843 us; speedup vs baseline: 1.7605x; 1.0830x over previous
//
#include <hip/hip_runtime.h>

#define NPADC 40
#define NZ 26
#define NXI 120            // interior nx (seismo width)
#define NZP 106
#define NXP 200
#define NCELL (NZP * NXP)

#define KSTEPS 5
#define HALO (2 * KSTEPS)          // 10
#define TZ 14
#define TX 25
#define ZB 8                       // 7*14=98, last tile tz=8
#define XB 8                       // 200/25 exact
#define NBLOCKS (ZB * XB)          // 64
#define EXT_X (TX + 2 * HALO)      // 45
#define EZMAX (TZ + 2 * HALO)      // 34
#define LDSN (EZMAX * EXT_X)       // 1530
#define NTHREADS 512
#define SLOTS 3                    // ceil(LDSN / NTHREADS)

// ---- damp profile, matching _damp_profile in fp32 ----
__device__ __forceinline__ float dprof(int idx, int n) {
#pragma clang fp contract(off)
    float fi = (float)idx;
    float left = 1.0f, right = 1.0f;
    if (idx < NPADC) {
        float a = 0.015f * ((float)NPADC - fi);
        left = expf(-(a * a));
    }
    if (idx >= n - NPADC) {
        float a = 0.015f * (fi - (float)(n - NPADC - 1));
        right = expf(-(a * a));
    }
    return left * right;
}

// ---- one-time setup: coefficients into ws, init state buf0, zero sync ----
__global__ void setup_kernel(const float* __restrict__ vp,
                             const float* __restrict__ vs,
                             const float* __restrict__ den,
                             const float* __restrict__ ivec,
                             const float* __restrict__ temp,
                             float* __restrict__ coeff,
                             float* __restrict__ buf0,
                             unsigned* __restrict__ flags,
                             unsigned* __restrict__ genp) {
#pragma clang fp contract(off)
    int i = blockIdx.x * blockDim.x + threadIdx.x;
    if (i <= NBLOCKS) {
        if (i < NBLOCKS) flags[i] = 0u; else *genp = 0u;
    }
    if (i >= NCELL) return;
    int z = i / NXP;
    int x = i - z * NXP;

    float dtx = ivec[3];

    int zi = z - NPADC; zi = zi < 0 ? 0 : (zi > NZ - 1 ? NZ - 1 : zi);
    int xi = x - NPADC; xi = xi < 0 ? 0 : (xi > NXI - 1 ? NXI - 1 : xi);
    float vpv = vp[zi * NXI + xi];
    float vsv = vs[zi * NXI + xi];
    float d = den[i];

    float cav = (vpv * vpv) * d;     // ca
    float cmv = (vsv * vsv) * d;     // cm
    coeff[0 * NCELL + i] = dtx / d;                        // b
    coeff[1 * NCELL + i] = dprof(z, NZP) * dprof(x, NXP);  // damp
    coeff[2 * NCELL + i] = cav;                            // ca
    coeff[3 * NCELL + i] = cav - 2.0f * cmv;               // cl
    coeff[4 * NCELL + i] = dtx * cmv;                      // dtx*cm

    for (int f = 0; f < 5; ++f)
        buf0[f * NCELL + i] = temp[f * NCELL + i];
}

// lds field order: 0=vx 1=vz 2=txx 3=tzz 4=txz 5=b 6=damp 7=ca 8=cl 9=dtcm
__global__ __launch_bounds__(NTHREADS)
void persist_kernel(const float* __restrict__ coeff,
                    float* __restrict__ buf0, float* __restrict__ buf1,
                    const float* __restrict__ ivec, const float* __restrict__ s,
                    const int* __restrict__ iszp, const int* __restrict__ isxp,
                    float* __restrict__ fields_out,
                    float* __restrict__ illum_out,
                    float* __restrict__ seismo,
                    unsigned* __restrict__ flags, unsigned* __restrict__ genp,
                    int nt) {
#pragma clang fp contract(off)
    __shared__ float lds[10][LDSN];
    __shared__ float lill[TZ * TX];

    const int tid = threadIdx.x;
    const int bid = blockIdx.x;
    const int zb = bid / XB, xb = bid - zb * XB;
    const int z0 = zb * TZ, x0 = xb * TX;
    const int tzb = (NZP - z0 < TZ) ? (NZP - z0) : TZ;   // 14 or 8
    const int ez = tzb + 2 * HALO;
    const int ncells = ez * EXT_X;
    const float dt  = ivec[2];
    const float dtx = ivec[3];
    const int isz = *iszp, isx = *isxp;

    // ---- per-thread slot precompute (coords, wrap, ownership) ----
    int rcA[SLOTS], gA[SLOTS], izA[SLOTS], ixA[SLOTS], seisA[SLOTS], lilA[SLOTS];
    for (int k = 0; k < SLOTS; ++k) {
        int rc = tid + k * NTHREADS;
        rcA[k] = rc;
        if (rc < ncells) {
            int iz = rc / EXT_X, ix = rc - iz * EXT_X;
            izA[k] = iz; ixA[k] = ix;
            int gz = z0 - HALO + iz; gz += (gz < 0) ? NZP : 0; gz -= (gz >= NZP) ? NZP : 0;
            int gx = x0 - HALO + ix; gx += (gx < 0) ? NXP : 0; gx -= (gx >= NXP) ? NXP : 0;
            gA[k] = gz * NXP + gx;
            int liz = iz - HALO, lix = ix - HALO;
            bool inter = (liz >= 0 && liz < tzb && lix >= 0 && lix < TX);
            int gzi = z0 + liz, gxi = x0 + lix;
            seisA[k] = (inter && gzi == NPADC + 1 && gxi >= NPADC && gxi < NPADC + NXI)
                           ? (gxi - NPADC) : -1;
            lilA[k] = inter ? (liz * TX + lix) : -1;
        } else {
            izA[k] = -1000; ixA[k] = -1000; gA[k] = 0; seisA[k] = -1; lilA[k] = -1;
        }
    }
    // source cell local index (each global cell appears at most once in ext tile)
    int lzs = isz - (z0 - HALO); lzs = ((lzs % NZP) + NZP) % NZP;
    int lxs = isx - (x0 - HALO); lxs = ((lxs % NXP) + NXP) % NXP;
    const int src_rc = (lzs < ez && lxs < EXT_X) ? lzs * EXT_X + lxs : -1;

    // interior store slot (tzb*TX <= 350 < NTHREADS: one slot)
    int st_g = -1, st_e = 0, st_l = 0;
    if (tid < tzb * TX) {
        int liz = tid / TX, lix = tid - liz * TX;
        st_g = (z0 + liz) * NXP + (x0 + lix);
        st_e = (liz + HALO) * EXT_X + (lix + HALO);
        st_l = tid;
    }

    // ---- coefficients: load once ----
    for (int k = 0; k < SLOTS; ++k) if (rcA[k] < ncells) {
        int rc = rcA[k], g = gA[k];
        lds[5][rc] = coeff[0 * NCELL + g];
        lds[6][rc] = coeff[1 * NCELL + g];
        lds[7][rc] = coeff[2 * NCELL + g];
        lds[8][rc] = coeff[3 * NCELL + g];
        lds[9][rc] = coeff[4 * NCELL + g];
    }
    for (int rc = tid; rc < tzb * TX; rc += NTHREADS) lill[rc] = 0.0f;

    // ---- time loop: K-step trapezoid chunks, grid barrier between ----
    int t0 = 0, parity = 0;
    unsigned chunk = 0;
    while (t0 < nt) {
        const int ks = (nt - t0 >= KSTEPS) ? KSTEPS : (nt - t0);
        const bool last = (t0 + ks >= nt);
        const float* srcb = parity ? buf1 : buf0;
        float* dstb = last ? fields_out : (parity ? buf0 : buf1);

        for (int k = 0; k < SLOTS; ++k) if (rcA[k] < ncells) {
            int rc = rcA[k], g = gA[k];
            lds[0][rc] = srcb[0 * NCELL + g];
            lds[1][rc] = srcb[1 * NCELL + g];
            lds[2][rc] = srcb[2 * NCELL + g];
            lds[3][rc] = srcb[3 * NCELL + g];
            lds[4][rc] = srcb[4 * NCELL + g];
        }
        __syncthreads();

        for (int p = 1; p <= 2 * ks; ++p) {
            const int t = t0 + ((p + 1) >> 1) - 1;
            const int lo = p, hiZ = ez - p, hiX = EXT_X - p;
            if (p & 1) {
                // velocity phase
                for (int k = 0; k < SLOTS; ++k) {
                    int iz = izA[k], ix = ixA[k];
                    if (iz < lo || iz >= hiZ || ix < lo || ix >= hiX) continue;
                    int rc = rcA[k];
                    float bv = lds[5][rc], dv = lds[6][rc];
                    float t1 = lds[2][rc + 1]     - lds[2][rc];
                    float t2 = lds[4][rc]         - lds[4][rc - EXT_X];
                    float nvx = (lds[0][rc] + bv * (t1 + t2)) * dv;
                    float t3 = lds[3][rc + EXT_X] - lds[3][rc];
                    float t4 = lds[4][rc]         - lds[4][rc - 1];
                    float nvz = (lds[1][rc] + bv * (t3 + t4)) * dv;
                    lds[0][rc] = nvx;
                    lds[1][rc] = nvz;
                    if (seisA[k] >= 0) seismo[t * NXI + seisA[k]] = nvz;
                }
            } else {
                // stress phase
                for (int k = 0; k < SLOTS; ++k) {
                    int iz = izA[k], ix = ixA[k];
                    if (iz < lo || iz >= hiZ || ix < lo || ix >= hiX) continue;
                    int rc = rcA[k];
                    float dv = lds[6][rc];
                    float exx = lds[0][rc] - lds[0][rc - 1];
                    float ezz = lds[1][rc] - lds[1][rc - EXT_X];
                    float e1 = lds[7][rc] * exx;
                    float e2 = lds[8][rc] * ezz;
                    float ntxx = (lds[2][rc] + dtx * (e1 + e2)) * dv;
                    float e3 = lds[8][rc] * exx;
                    float e4 = lds[7][rc] * ezz;
                    float ntzz = (lds[3][rc] + dtx * (e3 + e4)) * dv;
                    float p1 = lds[0][rc + EXT_X] - lds[0][rc];
                    float p2 = lds[1][rc + 1]     - lds[1][rc];
                    float ntxz = (lds[4][rc] + lds[9][rc] * (p1 + p2)) * dv;
                    if (rcA[k] == src_rc) {
                        float sv = s[t] * dt;
                        ntxx += sv;
                        ntzz += sv;
                    }
                    lds[2][rc] = ntxx;
                    lds[3][rc] = ntzz;
                    lds[4][rc] = ntxz;
                    if (lilA[k] >= 0) {
                        float divv = exx + ezz;
                        lill[lilA[k]] += divv * divv;
                    }
                }
            }
            __syncthreads();
        }

        // store interior
        if (st_g >= 0) {
            dstb[0 * NCELL + st_g] = lds[0][st_e];
            dstb[1 * NCELL + st_g] = lds[1][st_e];
            dstb[2 * NCELL + st_g] = lds[2][st_e];
            dstb[3 * NCELL + st_g] = lds[3][st_e];
            dstb[4 * NCELL + st_g] = lds[4][st_e];
            if (last) illum_out[st_g] = lill[st_l];
        }

        t0 += ks; parity ^= 1; ++chunk;

        if (!last) {
            // ---- grid barrier: per-block flag + master-wave poll ----
            __syncthreads();  // all stores of this block issued & drained
            if (tid == 0)
                __hip_atomic_store(&flags[bid], chunk, __ATOMIC_RELEASE,
                                   __HIP_MEMORY_SCOPE_AGENT);
            if (bid == 0 && tid < NBLOCKS) {
                while (__hip_atomic_load(&flags[tid], __ATOMIC_RELAXED,
                                         __HIP_MEMORY_SCOPE_AGENT) < chunk)
                    __builtin_amdgcn_s_sleep(1);
                (void)__hip_atomic_load(&flags[tid], __ATOMIC_ACQUIRE,
                                        __HIP_MEMORY_SCOPE_AGENT);
                if (tid == 0)
                    __hip_atomic_store(genp, chunk, __ATOMIC_RELEASE,
                                       __HIP_MEMORY_SCOPE_AGENT);
            }
            if (bid != 0 && tid == 0) {
                while (__hip_atomic_load(genp, __ATOMIC_RELAXED,
                                         __HIP_MEMORY_SCOPE_AGENT) < chunk)
                    __builtin_amdgcn_s_sleep(1);
                (void)__hip_atomic_load(genp, __ATOMIC_ACQUIRE,
                                        __HIP_MEMORY_SCOPE_AGENT);
            }
            __syncthreads();
        }
    }
}

extern "C" void kernel_launch(void* const* d_in, const int* in_sizes, int n_in,
                              void* d_out, int out_size, void* d_ws, size_t ws_size,
                              hipStream_t stream) {
    const float* vp   = (const float*)d_in[0];
    const float* vs   = (const float*)d_in[1];
    const float* den  = (const float*)d_in[2];
    const float* ivec = (const float*)d_in[3];
    const float* temp = (const float*)d_in[4];
    const float* s    = (const float*)d_in[5];
    const int*   isz  = (const int*)d_in[7];
    const int*   isx  = (const int*)d_in[8];
    int nt = in_sizes[5];

    float* out    = (float*)d_out;
    float* fields = out;                        // uu1: 5*NCELL
    float* seismo = out + 5 * NCELL;            // nt*NXI
    float* illum  = seismo + (size_t)nt * NXI;  // NCELL

    float* ws    = (float*)d_ws;
    float* coeff = ws;                 // 5*NCELL
    float* buf0  = ws + 5 * NCELL;     // 5*NCELL
    float* buf1  = ws + 10 * NCELL;    // 5*NCELL
    unsigned* flags = (unsigned*)(ws + 15 * NCELL);   // NBLOCKS
    unsigned* genp  = flags + NBLOCKS;                // 1

    setup_kernel<<<(NCELL + 255) / 256, 256, 0, stream>>>(
        vp, vs, den, ivec, temp, coeff, buf0, flags, genp);

    persist_kernel<<<NBLOCKS, NTHREADS, 0, stream>>>(
        coeff, buf0, buf1, ivec, s, isz, isx,
        fields, illum, seismo, flags, genp, nt);
}